// Round 6
// baseline (483.928 us; speedup 1.0000x reference)
//
#include <hip/hip_runtime.h>
#include <math.h>

#ifndef M_PI
#define M_PI 3.14159265358979323846
#endif

#define T 2048
#define EDGE 256
#define TT 1536            // trimmed timesteps
#define PHA_N 50
#define AMP_N 30
#define NBANDS 80
#define NBINS 18
#define NBC 16             // B*C = 2*8
#define FMAX 768           // forward DFT bins stored [0, FMAX); max needed bin = 634
#define NCH 16             // t-chunks for forward DFT
#define CHLEN (T / NCH)    // 128
#define QS 4               // t-quarters for mi_part
#define QT (TT / QS)       // 384

// Inclusive frequency-bin range [fl, fh] for a band, replicating the
// reference's float32 band edges vs exact quarter-Hz freq grid.
__device__ __forceinline__ void band_range(int band, int* fl, int* fh) {
    double lo, hi;
    if (band < PHA_N) {
        double mid = 2.0 + (double)band * (18.0 / 49.0);   // linspace(2,20,50)
        lo = (double)(float)(mid * 0.75);
        hi = (double)(float)(mid * 1.25);
    } else {
        int j = band - PHA_N;
        double mid = 60.0 + (double)j * (81.0 / 29.0);     // linspace(60,141,30)
        lo = (double)(float)(mid * 0.875);
        hi = (double)(float)(mid * 1.125);
    }
    int l = (int)ceil(lo * 4.0);     // freq = 0.25*f ; f >= 4*lo
    int h = (int)floor(hi * 4.0);    // f <= 4*hi
    if (l < 1) l = 1;
    if (h > FMAX - 1) h = FMAX - 1;
    *fl = l; *fh = h;
}

// Kernel 0: 2048th-roots-of-unity table, double and float. Runs once per call.
__global__ void init_kernel(double2* __restrict__ W, float2* __restrict__ Wf) {
    const int i = blockIdx.x * 256 + threadIdx.x;   // 0..2047
    double s, c;
    sincos((2.0 * M_PI / (double)T) * (double)i, &s, &c);
    W[i] = make_double2(c, s);
    Wf[i] = make_float2((float)c, (float)s);
}

// Kernel A: chunked forward DFT partials via complex oscillator recurrence.
__global__ void dft_kernel(const float* __restrict__ x,
                           const double2* __restrict__ W,
                           double* __restrict__ Xp) {
    __shared__ float xs[CHLEN + 8];        // pad 8 floats (2 float4) of zeros
    const int bc = blockIdx.x;
    const int fb = blockIdx.y;
    const int ch = blockIdx.z;
    const int tid = threadIdx.x;
    const int t0 = ch * CHLEN;
    if (tid < CHLEN) xs[tid] = x[bc * T + t0 + tid];
    if (tid < 8) xs[CHLEN + tid] = 0.0f;
    __syncthreads();
    const int f = fb * 256 + tid;
    const double2 c0 = W[(f * t0) & (T - 1)];
    const double2 ww = W[f & (T - 1)];
    double curR = c0.x, curI = -c0.y;      // e^{-i om f t0}
    const double wR = ww.x, wI = -ww.y;    // e^{-i om f}
    double accR = 0.0, accI = 0.0;
    const float4* xs4 = (const float4*)xs;
    float4 a0 = xs4[0], a1 = xs4[1];
    for (int q = 0; q < CHLEN / 4; ++q) {
        float4 a2 = xs4[q + 2];            // prefetch, used 2 iters later
        #pragma unroll
        for (int u = 0; u < 4; ++u) {
            double v = (double)((u == 0) ? a0.x : (u == 1) ? a0.y : (u == 2) ? a0.z : a0.w);
            accR += v * curR;
            accI += v * curI;
            double nR = curR * wR - curI * wI;
            double nI = curR * wI + curI * wR;
            curR = nR; curI = nI;
        }
        a0 = a1; a1 = a2;
    }
    Xp[(size_t)((bc * FMAX + f) * NCH + ch) * 2 + 0] = accR;
    Xp[(size_t)((bc * FMAX + f) * NCH + ch) * 2 + 1] = accI;
}

// Kernel A2: reduce NCH chunk partials -> Xf[bc][f] (complex double)
__global__ void reduce_kernel(const double* __restrict__ Xp, double* __restrict__ Xf) {
    const int gid = blockIdx.x * 256 + threadIdx.x;   // 0..12287 = bc*FMAX+f
    const double* p = Xp + (size_t)gid * NCH * 2;
    double r = 0.0, im = 0.0;
    #pragma unroll
    for (int c = 0; c < NCH; ++c) { r += p[2 * c]; im += p[2 * c + 1]; }
    Xf[2 * gid + 0] = r;
    Xf[2 * gid + 1] = im;
}

// Kernel B: per (bc, band, t-half) analytic-signal synthesis via oscillator
// recurrence over band bins. Phase fp64 (bin decision); amp fp32. Twiddles
// from the W table (no sincos). Largest bands first (band = 79 - y).
#define NJ 3
__global__ void band_kernel(const double* __restrict__ Xf,
                            const double2* __restrict__ W,
                            const float2* __restrict__ Wf,
                            unsigned char* __restrict__ idx_buf,
                            float* __restrict__ amp_buf) {
    __shared__ double sXr[164];
    __shared__ double sXi[164];
    const int bc = blockIdx.x;
    const int band = (NBANDS - 1) - blockIdx.y;   // biggest bands first
    const int half = blockIdx.z;
    const int tid = threadIdx.x;
    int fl, fh;
    band_range(band, &fl, &fh);
    const int nb = fh - fl + 1;
    const int t00 = tid + half * 768 + EDGE;      // time for j=0

    if (band < PHA_N) {
        // ---------- fp64 phase path ----------
        for (int i = tid; i < nb; i += 256) {
            sXr[i] = Xf[(size_t)(bc * FMAX + fl + i) * 2 + 0];
            sXi[i] = Xf[(size_t)(bc * FMAX + fl + i) * 2 + 1];
        }
        __syncthreads();
        double curR[NJ], curI[NJ], wR[NJ], wI[NJ], accR[NJ], accI[NJ];
        {
            const double2 c0 = W[(fl * t00) & (T - 1)];
            const double2 w0 = W[t00 & (T - 1)];
            const double2 sc = W[(fl << 8) & (T - 1)];   // e^{i om fl 256} (uniform)
            const double2 sw = W[256];                    // e^{i om 256}   (uniform)
            curR[0] = c0.x; curI[0] = c0.y;
            wR[0] = w0.x;  wI[0] = w0.y;
            #pragma unroll
            for (int j = 1; j < NJ; ++j) {
                curR[j] = curR[j-1] * sc.x - curI[j-1] * sc.y;
                curI[j] = curR[j-1] * sc.y + curI[j-1] * sc.x;
                wR[j]  = wR[j-1] * sw.x - wI[j-1] * sw.y;
                wI[j]  = wR[j-1] * sw.y + wI[j-1] * sw.x;
            }
            #pragma unroll
            for (int j = 0; j < NJ; ++j) { accR[j] = 0.0; accI[j] = 0.0; }
        }
        #pragma unroll 2
        for (int i = 0; i < nb; ++i) {
            const double Xr = sXr[i], Xi = sXi[i];   // broadcast read
            #pragma unroll
            for (int j = 0; j < NJ; ++j) {
                accR[j] += Xr * curR[j] - Xi * curI[j];
                accI[j] += Xr * curI[j] + Xi * curR[j];
                double nR = curR[j] * wR[j] - curI[j] * wI[j];
                double nI = curR[j] * wI[j] + curI[j] * wR[j];
                curR[j] = nR; curI[j] = nI;
            }
        }
        const double width = 2.0 * M_PI / (double)NBINS;
        #pragma unroll
        for (int j = 0; j < NJ; ++j) {
            const int trel = tid + j * 256 + half * 768;
            double pha = atan2(accI[j], accR[j]);        // (-pi, pi]
            int b = (int)floor((pha + M_PI) / width);
            if (b < 0) b = 0;
            if (b > NBINS - 1) b = NBINS - 1;
            idx_buf[(size_t)(bc * PHA_N + band) * TT + trel] = (unsigned char)b;
        }
    } else {
        // ---------- fp32 amplitude path ----------
        float* fXr = (float*)sXr;
        float* fXi = (float*)sXi;
        for (int i = tid; i < nb; i += 256) {
            fXr[i] = (float)Xf[(size_t)(bc * FMAX + fl + i) * 2 + 0];
            fXi[i] = (float)Xf[(size_t)(bc * FMAX + fl + i) * 2 + 1];
        }
        __syncthreads();
        float curR[NJ], curI[NJ], wRf[NJ], wIf[NJ], accR[NJ], accI[NJ];
        {
            const float2 c0 = Wf[(fl * t00) & (T - 1)];
            const float2 w0 = Wf[t00 & (T - 1)];
            const float2 sc = Wf[(fl << 8) & (T - 1)];
            const float2 sw = Wf[256];
            curR[0] = c0.x; curI[0] = c0.y;
            wRf[0] = w0.x;  wIf[0] = w0.y;
            #pragma unroll
            for (int j = 1; j < NJ; ++j) {
                curR[j] = curR[j-1] * sc.x - curI[j-1] * sc.y;
                curI[j] = curR[j-1] * sc.y + curI[j-1] * sc.x;
                wRf[j] = wRf[j-1] * sw.x - wIf[j-1] * sw.y;
                wIf[j] = wRf[j-1] * sw.y + wIf[j-1] * sw.x;
            }
            #pragma unroll
            for (int j = 0; j < NJ; ++j) { accR[j] = 0.0f; accI[j] = 0.0f; }
        }
        #pragma unroll 2
        for (int i = 0; i < nb; ++i) {
            const float Xr = fXr[i], Xi = fXi[i];
            #pragma unroll
            for (int j = 0; j < NJ; ++j) {
                accR[j] += Xr * curR[j] - Xi * curI[j];
                accI[j] += Xr * curI[j] + Xi * curR[j];
                float nR = curR[j] * wRf[j] - curI[j] * wIf[j];
                float nI = curR[j] * wIf[j] + curI[j] * wRf[j];
                curR[j] = nR; curI[j] = nI;
            }
        }
        #pragma unroll
        for (int j = 0; j < NJ; ++j) {
            const int trel = tid + j * 256 + half * 768;
            float amp = sqrtf(accR[j] * accR[j] + accI[j] * accI[j]) * (2.0f / (float)T);
            amp_buf[(size_t)(bc * AMP_N + (band - PHA_N)) * TT + trel] = amp;
        }
    }
}

// Kernel C1: per (bc, phase band p, t-quarter): fused counts + bin sums.
// idx staged in LDS once; private rows updated with ds_add_f32 atomics
// (fire-and-forget -> no read-modify-write dependency chain).
#define PK 19   // padded bin stride for partials
#define NROW 31 // 30 amp bands + counts row
__global__ void mi_part(const unsigned char* __restrict__ idx_buf,
                        const float* __restrict__ amp_buf,
                        float* __restrict__ Sums) {
    __shared__ float part[NROW * 8 * PK];     // row = tid = a*8+g
    __shared__ unsigned int sidx_s[QT / 4];   // 96 packed idx words
    const int blk = blockIdx.x;               // bc*50 + p
    const int q = blockIdx.y;                 // t-quarter
    const int bc = blk / PHA_N;
    const int p = blk % PHA_N;
    const int tid = threadIdx.x;

    for (int i = tid; i < NROW * 8 * PK; i += 256) part[i] = 0.0f;
    if (tid < QT / 4)
        sidx_s[tid] = ((const unsigned int*)(idx_buf + (size_t)(bc * PHA_N + p) * TT + q * QT))[tid];
    __syncthreads();

    if (tid < NROW * 8) {
        const int a = tid >> 3;     // 0..30 (30 == counts row)
        const int g = tid & 7;      // contiguous 48-t chunk per thread
        const float4* ap = (a < AMP_N)
            ? (const float4*)(amp_buf + (size_t)(bc * AMP_N + a) * TT + q * QT) + g * 12
            : (const float4*)0;
        float* myp = part + tid * PK;
        for (int it = 0; it < 12; ++it) {
            const unsigned int pk = sidx_s[g * 12 + it];   // LDS broadcast
            float4 v;
            if (a < AMP_N) v = ap[it];
            else { v.x = 1.0f; v.y = 1.0f; v.z = 1.0f; v.w = 1.0f; }
            atomicAdd(&myp[pk & 0xff], v.x);
            atomicAdd(&myp[(pk >> 8) & 0xff], v.y);
            atomicAdd(&myp[(pk >> 16) & 0xff], v.z);
            atomicAdd(&myp[(pk >> 24) & 0xff], v.w);
        }
    }
    __syncthreads();

    for (int i = tid; i < NROW * NBINS; i += 256) {
        const int row = i / NBINS, k = i - row * NBINS;
        float s = 0.0f;
        #pragma unroll
        for (int g = 0; g < 8; ++g) s += part[(row * 8 + g) * PK + k];
        atomicAdd(&Sums[((size_t)blk * NROW + row) * NBINS + k], s);
    }
}

// Kernel C2: MI from Sums. One thread per (pair, amp band).
__global__ void mi_final(const float* __restrict__ Sums, float* __restrict__ out) {
    const int gid = blockIdx.x * 256 + threadIdx.x;
    if (gid >= NBC * PHA_N * AMP_N) return;
    const int pair = gid / AMP_N;
    const int a = gid - pair * AMP_N;
    const float* srow = Sums + ((size_t)pair * NROW + a) * NBINS;
    const float* crow = Sums + ((size_t)pair * NROW + AMP_N) * NBINS;   // counts
    double m[NBINS], tot = 0.0;
    #pragma unroll
    for (int k = 0; k < NBINS; ++k) {
        double cnt = (double)crow[k];
        double denom = cnt > 1e-9 ? cnt : 1e-9;
        m[k] = (double)srow[k] / denom;
        tot += m[k];
    }
    double dt = tot > 1e-9 ? tot : 1e-9;
    double acc = 0.0;
    #pragma unroll
    for (int k = 0; k < NBINS; ++k) {
        double pr = m[k] / dt;
        acc += pr * log(pr + 1e-9);
    }
    const double lognb = log((double)NBINS);
    out[gid] = (float)((lognb + acc) / lognb);
}

extern "C" void kernel_launch(void* const* d_in, const int* in_sizes, int n_in,
                              void* d_out, int out_size, void* d_ws, size_t ws_size,
                              hipStream_t stream) {
    const float* x = (const float*)d_in[0];
    float* out = (float*)d_out;
    char* ws = (char*)d_ws;
    // workspace layout (~9.36 MB; all regions written before read each call):
    //   idx_buf: 16*50*1536 u8                       = 1,228,800 B @ 0
    //   amp_buf: 16*30*1536 f32                      = 2,949,120 B @ 1,228,800
    //   Xp:      16*768*16 chunks complex double     = 3,145,728 B @ 4,177,920
    //   Xf:      16*768 complex double               =   196,608 B @ 7,323,648
    //   Sums:    800*31*18 f32                       = 1,785,600 B @ 7,520,256
    //   W:       2048 double2                        =    32,768 B @ 9,305,856
    //   Wf:      2048 float2                         =    16,384 B @ 9,338,624
    unsigned char* idx_buf = (unsigned char*)ws;
    float* amp_buf = (float*)(ws + 1228800);
    double* Xp = (double*)(ws + 4177920);
    double* Xf = (double*)(ws + 7323648);
    float* Sums = (float*)(ws + 7520256);
    double2* W = (double2*)(ws + 9305856);
    float2* Wf = (float2*)(ws + 9338624);

    init_kernel<<<T / 256, 256, 0, stream>>>(W, Wf);
    hipMemsetAsync(Sums, 0, (size_t)NBC * PHA_N * NROW * NBINS * 4, stream);
    dft_kernel<<<dim3(NBC, FMAX / 256, NCH), 256, 0, stream>>>(x, W, Xp);
    reduce_kernel<<<NBC * FMAX / 256, 256, 0, stream>>>(Xp, Xf);
    band_kernel<<<dim3(NBC, NBANDS, 2), 256, 0, stream>>>(Xf, W, Wf, idx_buf, amp_buf);
    mi_part<<<dim3(NBC * PHA_N, QS), 256, 0, stream>>>(idx_buf, amp_buf, Sums);
    mi_final<<<(NBC * PHA_N * AMP_N + 255) / 256, 256, 0, stream>>>(Sums, out);
}

// Round 7
// 156.405 us; speedup vs baseline: 3.0941x; 3.0941x over previous
//
#include <hip/hip_runtime.h>
#include <math.h>

#ifndef M_PI
#define M_PI 3.14159265358979323846
#endif

#define T 2048
#define EDGE 256
#define TT 1536            // trimmed timesteps
#define PHA_N 50
#define AMP_N 30
#define NBANDS 80
#define NBINS 18
#define NBC 16             // B*C = 2*8
#define FMAX 768           // forward DFT bins stored [0, FMAX); max needed bin = 634
#define NCH 16             // t-chunks for forward DFT
#define CHLEN (T / NCH)    // 128
#define QS 4               // t-quarters for mi_part
#define QT (TT / QS)       // 384

// Inclusive frequency-bin range [fl, fh] for a band, replicating the
// reference's float32 band edges vs exact quarter-Hz freq grid.
__device__ __forceinline__ void band_range(int band, int* fl, int* fh) {
    double lo, hi;
    if (band < PHA_N) {
        double mid = 2.0 + (double)band * (18.0 / 49.0);   // linspace(2,20,50)
        lo = (double)(float)(mid * 0.75);
        hi = (double)(float)(mid * 1.25);
    } else {
        int j = band - PHA_N;
        double mid = 60.0 + (double)j * (81.0 / 29.0);     // linspace(60,141,30)
        lo = (double)(float)(mid * 0.875);
        hi = (double)(float)(mid * 1.125);
    }
    int l = (int)ceil(lo * 4.0);     // freq = 0.25*f ; f >= 4*lo
    int h = (int)floor(hi * 4.0);    // f <= 4*hi
    if (l < 1) l = 1;
    if (h > FMAX - 1) h = FMAX - 1;
    *fl = l; *fh = h;
}

// Kernel A: chunked forward DFT partials. Two independent 64-step oscillator
// chains per thread (ILP on the serial fp64 rotate). Xp layout: ch slowest ->
// adjacent lanes (consecutive f) write contiguous 16B (coalesced).
__global__ void dft_kernel(const float* __restrict__ x, double* __restrict__ Xp) {
    __shared__ float xs[CHLEN];
    const int bc = blockIdx.x;
    const int fb = blockIdx.y;
    const int ch = blockIdx.z;
    const int tid = threadIdx.x;
    const int t0 = ch * CHLEN;
    if (tid < CHLEN) xs[tid] = x[bc * T + t0 + tid];
    __syncthreads();
    const int f = fb * 256 + tid;
    const double om = 2.0 * M_PI / (double)T;
    double s, c;
    sincos(om * (double)(f & (T - 1)), &s, &c);
    const double wR = c, wI = -s;                       // e^{-i om f}
    double curR[2], curI[2], accR[2], accI[2];
    #pragma unroll
    for (int h = 0; h < 2; ++h) {
        sincos(om * (double)((f * (t0 + h * 64)) & (T - 1)), &s, &c);
        curR[h] = c; curI[h] = -s;                      // e^{-i om f (t0+64h)}
        accR[h] = 0.0; accI[h] = 0.0;
    }
    #pragma unroll 2
    for (int t = 0; t < 64; ++t) {
        #pragma unroll
        for (int h = 0; h < 2; ++h) {
            double v = (double)xs[t + h * 64];
            accR[h] += v * curR[h];
            accI[h] += v * curI[h];
            double nR = curR[h] * wR - curI[h] * wI;
            double nI = curR[h] * wI + curI[h] * wR;
            curR[h] = nR; curI[h] = nI;
        }
    }
    const size_t o = (size_t)((ch * NBC + bc) * FMAX + f) * 2;
    Xp[o + 0] = accR[0] + accR[1];
    Xp[o + 1] = accI[0] + accI[1];
}

// Kernel A2: reduce NCH chunk partials -> Xf[bc][f]. Coalesced: per-c reads
// are contiguous across gid.
__global__ void reduce_kernel(const double* __restrict__ Xp, double* __restrict__ Xf) {
    const int gid = blockIdx.x * 256 + threadIdx.x;   // 0..12287 = bc*FMAX+f
    double r = 0.0, im = 0.0;
    #pragma unroll
    for (int c = 0; c < NCH; ++c) {
        r  += Xp[((size_t)c * NBC * FMAX + gid) * 2 + 0];
        im += Xp[((size_t)c * NBC * FMAX + gid) * 2 + 1];
    }
    Xf[2 * gid + 0] = r;
    Xf[2 * gid + 1] = im;
}

// Kernel B (R5 verbatim): per (bc, band, t-half) analytic-signal synthesis.
// Phase bands fp64 (bin decision); amp bands fp32. Largest bands first.
#define NJ 3
__global__ void band_kernel(const double* __restrict__ Xf,
                            unsigned char* __restrict__ idx_buf,
                            float* __restrict__ amp_buf) {
    __shared__ double sXr[164];
    __shared__ double sXi[164];
    const int bc = blockIdx.x;
    const int band = (NBANDS - 1) - blockIdx.y;   // biggest bands first
    const int half = blockIdx.z;
    const int tid = threadIdx.x;
    int fl, fh;
    band_range(band, &fl, &fh);
    const int nb = fh - fl + 1;
    const double om = 2.0 * M_PI / (double)T;

    if (band < PHA_N) {
        // ---------- fp64 phase path ----------
        for (int i = tid; i < nb; i += 256) {
            sXr[i] = Xf[(size_t)(bc * FMAX + fl + i) * 2 + 0];
            sXi[i] = Xf[(size_t)(bc * FMAX + fl + i) * 2 + 1];
        }
        __syncthreads();
        double curR[NJ], curI[NJ], wR[NJ], wI[NJ], accR[NJ], accI[NJ];
        #pragma unroll
        for (int j = 0; j < NJ; ++j) {
            const int t = tid + j * 256 + half * 768 + EDGE;
            double s, c;
            sincos(om * (double)((fl * t) & (T - 1)), &s, &c);
            curR[j] = c; curI[j] = s;          // e^{+i om fl t}
            sincos(om * (double)(t & (T - 1)), &s, &c);
            wR[j] = c; wI[j] = s;              // e^{+i om t}
            accR[j] = 0.0; accI[j] = 0.0;
        }
        #pragma unroll 2
        for (int i = 0; i < nb; ++i) {
            const double Xr = sXr[i], Xi = sXi[i];   // broadcast read
            #pragma unroll
            for (int j = 0; j < NJ; ++j) {
                accR[j] += Xr * curR[j] - Xi * curI[j];
                accI[j] += Xr * curI[j] + Xi * curR[j];
                double nR = curR[j] * wR[j] - curI[j] * wI[j];
                double nI = curR[j] * wI[j] + curI[j] * wR[j];
                curR[j] = nR; curI[j] = nI;
            }
        }
        const double width = 2.0 * M_PI / (double)NBINS;
        #pragma unroll
        for (int j = 0; j < NJ; ++j) {
            const int trel = tid + j * 256 + half * 768;
            double pha = atan2(accI[j], accR[j]);        // (-pi, pi]
            int b = (int)floor((pha + M_PI) / width);
            if (b < 0) b = 0;
            if (b > NBINS - 1) b = NBINS - 1;
            idx_buf[(size_t)(bc * PHA_N + band) * TT + trel] = (unsigned char)b;
        }
    } else {
        // ---------- fp32 amplitude path ----------
        float* fXr = (float*)sXr;
        float* fXi = (float*)sXi;
        for (int i = tid; i < nb; i += 256) {
            fXr[i] = (float)Xf[(size_t)(bc * FMAX + fl + i) * 2 + 0];
            fXi[i] = (float)Xf[(size_t)(bc * FMAX + fl + i) * 2 + 1];
        }
        __syncthreads();
        float curR[NJ], curI[NJ], wRf[NJ], wIf[NJ], accR[NJ], accI[NJ];
        #pragma unroll
        for (int j = 0; j < NJ; ++j) {
            const int t = tid + j * 256 + half * 768 + EDGE;
            double s, c;
            sincos(om * (double)((fl * t) & (T - 1)), &s, &c);
            curR[j] = (float)c; curI[j] = (float)s;
            sincos(om * (double)(t & (T - 1)), &s, &c);
            wRf[j] = (float)c; wIf[j] = (float)s;
            accR[j] = 0.0f; accI[j] = 0.0f;
        }
        #pragma unroll 2
        for (int i = 0; i < nb; ++i) {
            const float Xr = fXr[i], Xi = fXi[i];
            #pragma unroll
            for (int j = 0; j < NJ; ++j) {
                accR[j] += Xr * curR[j] - Xi * curI[j];
                accI[j] += Xr * curI[j] + Xi * curR[j];
                float nR = curR[j] * wRf[j] - curI[j] * wIf[j];
                float nI = curR[j] * wIf[j] + curI[j] * wRf[j];
                curR[j] = nR; curI[j] = nI;
            }
        }
        #pragma unroll
        for (int j = 0; j < NJ; ++j) {
            const int trel = tid + j * 256 + half * 768;
            float amp = sqrtf(accR[j] * accR[j] + accI[j] * accI[j]) * (2.0f / (float)T);
            amp_buf[(size_t)(bc * AMP_N + (band - PHA_N)) * TT + trel] = amp;
        }
    }
}

// Kernel C1: per (bc, phase band p, t-quarter): counts + bin sums with
// 18 REGISTER accumulators per thread (cmp/cndmask/add over bins) —
// no data-dependent LDS addressing, no RMW chains, no atomic CAS.
#define NROW 31 // 30 amp bands + counts row
__global__ void mi_part(const unsigned char* __restrict__ idx_buf,
                        const float* __restrict__ amp_buf,
                        float* __restrict__ Sums) {
    __shared__ float part[NROW * 8 * NBINS];  // [row=a*8+g][k]
    __shared__ unsigned int sidx_s[QT / 4];   // 96 packed idx words
    const int blk = blockIdx.x;               // bc*50 + p
    const int q = blockIdx.y;                 // t-quarter
    const int bc = blk / PHA_N;
    const int p = blk % PHA_N;
    const int tid = threadIdx.x;

    if (tid < QT / 4)
        sidx_s[tid] = ((const unsigned int*)(idx_buf + (size_t)(bc * PHA_N + p) * TT + q * QT))[tid];
    __syncthreads();

    if (tid < NROW * 8) {
        const int a = tid >> 3;     // 0..30 (30 == counts row)
        const int g = tid & 7;      // contiguous 48-t chunk per thread
        const float4* ap = (const float4*)(amp_buf + (size_t)(bc * AMP_N + a) * TT + q * QT) + g * 12;
        float acc[NBINS];
        #pragma unroll
        for (int k = 0; k < NBINS; ++k) acc[k] = 0.0f;
        for (int it = 0; it < 12; ++it) {
            const unsigned int pk = sidx_s[g * 12 + it];   // LDS broadcast
            float4 v;
            if (a < AMP_N) v = ap[it];
            else { v.x = 1.0f; v.y = 1.0f; v.z = 1.0f; v.w = 1.0f; }
            const int b0 = pk & 0xff, b1 = (pk >> 8) & 0xff;
            const int b2 = (pk >> 16) & 0xff, b3 = (pk >> 24) & 0xff;
            #pragma unroll
            for (int k = 0; k < NBINS; ++k) {
                acc[k] += (b0 == k) ? v.x : 0.0f;
                acc[k] += (b1 == k) ? v.y : 0.0f;
                acc[k] += (b2 == k) ? v.z : 0.0f;
                acc[k] += (b3 == k) ? v.w : 0.0f;
            }
        }
        #pragma unroll
        for (int k = 0; k < NBINS; ++k) part[tid * NBINS + k] = acc[k];
    }
    __syncthreads();

    for (int i = tid; i < NROW * NBINS; i += 256) {
        const int row = i / NBINS, k = i - row * NBINS;
        float s = 0.0f;
        #pragma unroll
        for (int g = 0; g < 8; ++g) s += part[(row * 8 + g) * NBINS + k];
        atomicAdd(&Sums[((size_t)blk * NROW + row) * NBINS + k], s);
    }
}

// Kernel C2: MI from Sums. One thread per (pair, amp band).
__global__ void mi_final(const float* __restrict__ Sums, float* __restrict__ out) {
    const int gid = blockIdx.x * 256 + threadIdx.x;
    if (gid >= NBC * PHA_N * AMP_N) return;
    const int pair = gid / AMP_N;
    const int a = gid - pair * AMP_N;
    const float* srow = Sums + ((size_t)pair * NROW + a) * NBINS;
    const float* crow = Sums + ((size_t)pair * NROW + AMP_N) * NBINS;   // counts
    double m[NBINS], tot = 0.0;
    #pragma unroll
    for (int k = 0; k < NBINS; ++k) {
        double cnt = (double)crow[k];
        double denom = cnt > 1e-9 ? cnt : 1e-9;
        m[k] = (double)srow[k] / denom;
        tot += m[k];
    }
    double dt = tot > 1e-9 ? tot : 1e-9;
    double acc = 0.0;
    #pragma unroll
    for (int k = 0; k < NBINS; ++k) {
        double pr = m[k] / dt;
        acc += pr * log(pr + 1e-9);
    }
    const double lognb = log((double)NBINS);
    out[gid] = (float)((lognb + acc) / lognb);
}

extern "C" void kernel_launch(void* const* d_in, const int* in_sizes, int n_in,
                              void* d_out, int out_size, void* d_ws, size_t ws_size,
                              hipStream_t stream) {
    const float* x = (const float*)d_in[0];
    float* out = (float*)d_out;
    char* ws = (char*)d_ws;
    // workspace layout (~9.3 MB; all regions written before read each call):
    //   idx_buf: 16*50*1536 u8                       = 1,228,800 B @ 0
    //   amp_buf: 16*30*1536 f32                      = 2,949,120 B @ 1,228,800
    //   Xp:      16 chunks * 16*768 complex double   = 3,145,728 B @ 4,177,920
    //   Xf:      16*768 complex double               =   196,608 B @ 7,323,648
    //   Sums:    800*31*18 f32                       = 1,785,600 B @ 7,520,256
    unsigned char* idx_buf = (unsigned char*)ws;
    float* amp_buf = (float*)(ws + 1228800);
    double* Xp = (double*)(ws + 4177920);
    double* Xf = (double*)(ws + 7323648);
    float* Sums = (float*)(ws + 7520256);

    hipMemsetAsync(Sums, 0, (size_t)NBC * PHA_N * NROW * NBINS * 4, stream);
    dft_kernel<<<dim3(NBC, FMAX / 256, NCH), 256, 0, stream>>>(x, Xp);
    reduce_kernel<<<NBC * FMAX / 256, 256, 0, stream>>>(Xp, Xf);
    band_kernel<<<dim3(NBC, NBANDS, 2), 256, 0, stream>>>(Xf, idx_buf, amp_buf);
    mi_part<<<dim3(NBC * PHA_N, QS), 256, 0, stream>>>(idx_buf, amp_buf, Sums);
    mi_final<<<(NBC * PHA_N * AMP_N + 255) / 256, 256, 0, stream>>>(Sums, out);
}

// Round 8
// 148.257 us; speedup vs baseline: 3.2641x; 1.0550x over previous
//
#include <hip/hip_runtime.h>
#include <math.h>

#ifndef M_PI
#define M_PI 3.14159265358979323846
#endif

#define T 2048
#define EDGE 256
#define TT 1536            // trimmed timesteps
#define PHA_N 50
#define AMP_N 30
#define NBANDS 80
#define NBINS 18
#define NBC 16             // B*C = 2*8
#define FMAX 768           // forward DFT bins stored [0, FMAX); max needed bin = 634
#define NCH 16             // t-chunks for forward DFT
#define CHLEN (T / NCH)    // 128
#define QS 4               // t-quarters for mi_part
#define QT (TT / QS)       // 384
#define ASCALE 262144.0f   // 2^18 fixed-point scale for amp quantization

// Inclusive frequency-bin range [fl, fh] for a band, replicating the
// reference's float32 band edges vs exact quarter-Hz freq grid.
__device__ __forceinline__ void band_range(int band, int* fl, int* fh) {
    double lo, hi;
    if (band < PHA_N) {
        double mid = 2.0 + (double)band * (18.0 / 49.0);   // linspace(2,20,50)
        lo = (double)(float)(mid * 0.75);
        hi = (double)(float)(mid * 1.25);
    } else {
        int j = band - PHA_N;
        double mid = 60.0 + (double)j * (81.0 / 29.0);     // linspace(60,141,30)
        lo = (double)(float)(mid * 0.875);
        hi = (double)(float)(mid * 1.125);
    }
    int l = (int)ceil(lo * 4.0);     // freq = 0.25*f ; f >= 4*lo
    int h = (int)floor(hi * 4.0);    // f <= 4*hi
    if (l < 1) l = 1;
    if (h > FMAX - 1) h = FMAX - 1;
    *fl = l; *fh = h;
}

// Kernel A: chunked forward DFT partials. Two independent 64-step oscillator
// chains per thread; Xp layout ch-slowest for coalesced writes.
__global__ void dft_kernel(const float* __restrict__ x, double* __restrict__ Xp) {
    __shared__ float xs[CHLEN];
    const int bc = blockIdx.x;
    const int fb = blockIdx.y;
    const int ch = blockIdx.z;
    const int tid = threadIdx.x;
    const int t0 = ch * CHLEN;
    if (tid < CHLEN) xs[tid] = x[bc * T + t0 + tid];
    __syncthreads();
    const int f = fb * 256 + tid;
    const double om = 2.0 * M_PI / (double)T;
    double s, c;
    sincos(om * (double)(f & (T - 1)), &s, &c);
    const double wR = c, wI = -s;                       // e^{-i om f}
    double curR[2], curI[2], accR[2], accI[2];
    #pragma unroll
    for (int h = 0; h < 2; ++h) {
        sincos(om * (double)((f * (t0 + h * 64)) & (T - 1)), &s, &c);
        curR[h] = c; curI[h] = -s;                      // e^{-i om f (t0+64h)}
        accR[h] = 0.0; accI[h] = 0.0;
    }
    #pragma unroll 2
    for (int t = 0; t < 64; ++t) {
        #pragma unroll
        for (int h = 0; h < 2; ++h) {
            double v = (double)xs[t + h * 64];
            accR[h] += v * curR[h];
            accI[h] += v * curI[h];
            double nR = curR[h] * wR - curI[h] * wI;
            double nI = curR[h] * wI + curI[h] * wR;
            curR[h] = nR; curI[h] = nI;
        }
    }
    const size_t o = (size_t)((ch * NBC + bc) * FMAX + f) * 2;
    Xp[o + 0] = accR[0] + accR[1];
    Xp[o + 1] = accI[0] + accI[1];
}

// Kernel A2: reduce NCH chunk partials -> Xf[bc][f]. Coalesced.
__global__ void reduce_kernel(const double* __restrict__ Xp, double* __restrict__ Xf) {
    const int gid = blockIdx.x * 256 + threadIdx.x;   // 0..12287 = bc*FMAX+f
    double r = 0.0, im = 0.0;
    #pragma unroll
    for (int c = 0; c < NCH; ++c) {
        r  += Xp[((size_t)c * NBC * FMAX + gid) * 2 + 0];
        im += Xp[((size_t)c * NBC * FMAX + gid) * 2 + 1];
    }
    Xf[2 * gid + 0] = r;
    Xf[2 * gid + 1] = im;
}

// Kernel B: per (bc, band, t-half) analytic-signal synthesis.
// Phase bands fp64 (bin decision); amp bands fp32, stored as u32 fixed-point
// (amp * 2^18, round-nearest) for mi_part's integer LDS atomics.
#define NJ 3
__global__ void band_kernel(const double* __restrict__ Xf,
                            unsigned char* __restrict__ idx_buf,
                            unsigned int* __restrict__ ampu_buf) {
    __shared__ double sXr[164];
    __shared__ double sXi[164];
    const int bc = blockIdx.x;
    const int band = (NBANDS - 1) - blockIdx.y;   // biggest bands first
    const int half = blockIdx.z;
    const int tid = threadIdx.x;
    int fl, fh;
    band_range(band, &fl, &fh);
    const int nb = fh - fl + 1;
    const double om = 2.0 * M_PI / (double)T;

    if (band < PHA_N) {
        // ---------- fp64 phase path ----------
        for (int i = tid; i < nb; i += 256) {
            sXr[i] = Xf[(size_t)(bc * FMAX + fl + i) * 2 + 0];
            sXi[i] = Xf[(size_t)(bc * FMAX + fl + i) * 2 + 1];
        }
        __syncthreads();
        double curR[NJ], curI[NJ], wR[NJ], wI[NJ], accR[NJ], accI[NJ];
        #pragma unroll
        for (int j = 0; j < NJ; ++j) {
            const int t = tid + j * 256 + half * 768 + EDGE;
            double s, c;
            sincos(om * (double)((fl * t) & (T - 1)), &s, &c);
            curR[j] = c; curI[j] = s;          // e^{+i om fl t}
            sincos(om * (double)(t & (T - 1)), &s, &c);
            wR[j] = c; wI[j] = s;              // e^{+i om t}
            accR[j] = 0.0; accI[j] = 0.0;
        }
        #pragma unroll 2
        for (int i = 0; i < nb; ++i) {
            const double Xr = sXr[i], Xi = sXi[i];   // broadcast read
            #pragma unroll
            for (int j = 0; j < NJ; ++j) {
                accR[j] += Xr * curR[j] - Xi * curI[j];
                accI[j] += Xr * curI[j] + Xi * curR[j];
                double nR = curR[j] * wR[j] - curI[j] * wI[j];
                double nI = curR[j] * wI[j] + curI[j] * wR[j];
                curR[j] = nR; curI[j] = nI;
            }
        }
        const double width = 2.0 * M_PI / (double)NBINS;
        #pragma unroll
        for (int j = 0; j < NJ; ++j) {
            const int trel = tid + j * 256 + half * 768;
            double pha = atan2(accI[j], accR[j]);        // (-pi, pi]
            int b = (int)floor((pha + M_PI) / width);
            if (b < 0) b = 0;
            if (b > NBINS - 1) b = NBINS - 1;
            idx_buf[(size_t)(bc * PHA_N + band) * TT + trel] = (unsigned char)b;
        }
    } else {
        // ---------- fp32 amplitude path ----------
        float* fXr = (float*)sXr;
        float* fXi = (float*)sXi;
        for (int i = tid; i < nb; i += 256) {
            fXr[i] = (float)Xf[(size_t)(bc * FMAX + fl + i) * 2 + 0];
            fXi[i] = (float)Xf[(size_t)(bc * FMAX + fl + i) * 2 + 1];
        }
        __syncthreads();
        float curR[NJ], curI[NJ], wRf[NJ], wIf[NJ], accR[NJ], accI[NJ];
        #pragma unroll
        for (int j = 0; j < NJ; ++j) {
            const int t = tid + j * 256 + half * 768 + EDGE;
            double s, c;
            sincos(om * (double)((fl * t) & (T - 1)), &s, &c);
            curR[j] = (float)c; curI[j] = (float)s;
            sincos(om * (double)(t & (T - 1)), &s, &c);
            wRf[j] = (float)c; wIf[j] = (float)s;
            accR[j] = 0.0f; accI[j] = 0.0f;
        }
        #pragma unroll 2
        for (int i = 0; i < nb; ++i) {
            const float Xr = fXr[i], Xi = fXi[i];
            #pragma unroll
            for (int j = 0; j < NJ; ++j) {
                accR[j] += Xr * curR[j] - Xi * curI[j];
                accI[j] += Xr * curI[j] + Xi * curR[j];
                float nR = curR[j] * wRf[j] - curI[j] * wIf[j];
                float nI = curR[j] * wIf[j] + curI[j] * wRf[j];
                curR[j] = nR; curI[j] = nI;
            }
        }
        #pragma unroll
        for (int j = 0; j < NJ; ++j) {
            const int trel = tid + j * 256 + half * 768;
            float amp = sqrtf(accR[j] * accR[j] + accI[j] * accI[j]) * (2.0f / (float)T);
            ampu_buf[(size_t)(bc * AMP_N + (band - PHA_N)) * TT + trel] =
                (unsigned int)(amp * ASCALE + 0.5f);
        }
    }
}

// Kernel C1: per (bc, phase band p, t-quarter): counts + bin sums via native
// integer LDS atomics (ds_add_u32, fire-and-forget, no RMW chain, no CAS —
// float LDS atomicAdd lowers to a CAS loop, never use it here [R5 lesson]).
// Each thread owns a private LDS row -> zero same-address contention.
#define PK 19   // padded row stride
#define NROW 31 // 30 amp bands + counts row
__global__ void mi_part(const unsigned char* __restrict__ idx_buf,
                        const unsigned int* __restrict__ ampu_buf,
                        unsigned int* __restrict__ Sums) {
    __shared__ unsigned int part[NROW * 8 * PK];  // [row=a*8+g][k], u32 fixed-point
    __shared__ unsigned int sidx_s[QT / 4];       // 96 packed idx words
    const int blk = blockIdx.x;               // bc*50 + p
    const int q = blockIdx.y;                 // t-quarter
    const int bc = blk / PHA_N;
    const int p = blk % PHA_N;
    const int tid = threadIdx.x;

    for (int i = tid; i < NROW * 8 * PK; i += 256) part[i] = 0u;
    if (tid < QT / 4)
        sidx_s[tid] = ((const unsigned int*)(idx_buf + (size_t)(bc * PHA_N + p) * TT + q * QT))[tid];
    __syncthreads();

    if (tid < NROW * 8) {
        const int a = tid >> 3;     // 0..30 (30 == counts row)
        const int g = tid & 7;      // contiguous 48-t chunk per thread
        const uint4* ap = (const uint4*)(ampu_buf + (size_t)(bc * AMP_N + a) * TT + q * QT) + g * 12;
        unsigned int* myp = part + tid * PK;
        #pragma unroll
        for (int it = 0; it < 12; ++it) {
            const unsigned int pk = sidx_s[g * 12 + it];   // LDS broadcast
            uint4 v;
            if (a < AMP_N) v = ap[it];
            else { v.x = 1u; v.y = 1u; v.z = 1u; v.w = 1u; }
            atomicAdd(&myp[pk & 0xff], v.x);          // ds_add_u32, no return
            atomicAdd(&myp[(pk >> 8) & 0xff], v.y);
            atomicAdd(&myp[(pk >> 16) & 0xff], v.z);
            atomicAdd(&myp[(pk >> 24) & 0xff], v.w);
        }
    }
    __syncthreads();

    for (int i = tid; i < NROW * NBINS; i += 256) {
        const int row = i / NBINS, k = i - row * NBINS;
        unsigned int s = 0u;
        #pragma unroll
        for (int g = 0; g < 8; ++g) s += part[(row * 8 + g) * PK + k];
        atomicAdd(&Sums[((size_t)blk * NROW + row) * NBINS + k], s);   // global u32
    }
}

// Kernel C2: MI from Sums. One thread per (pair, amp band).
__global__ void mi_final(const unsigned int* __restrict__ Sums, float* __restrict__ out) {
    const int gid = blockIdx.x * 256 + threadIdx.x;
    if (gid >= NBC * PHA_N * AMP_N) return;
    const int pair = gid / AMP_N;
    const int a = gid - pair * AMP_N;
    const unsigned int* srow = Sums + ((size_t)pair * NROW + a) * NBINS;
    const unsigned int* crow = Sums + ((size_t)pair * NROW + AMP_N) * NBINS;   // counts
    const double inv_scale = 1.0 / (double)ASCALE;
    double m[NBINS], tot = 0.0;
    #pragma unroll
    for (int k = 0; k < NBINS; ++k) {
        double cnt = (double)crow[k];
        double denom = cnt > 1e-9 ? cnt : 1e-9;
        m[k] = ((double)srow[k] * inv_scale) / denom;
        tot += m[k];
    }
    double dt = tot > 1e-9 ? tot : 1e-9;
    double acc = 0.0;
    #pragma unroll
    for (int k = 0; k < NBINS; ++k) {
        double pr = m[k] / dt;
        acc += pr * log(pr + 1e-9);
    }
    const double lognb = log((double)NBINS);
    out[gid] = (float)((lognb + acc) / lognb);
}

extern "C" void kernel_launch(void* const* d_in, const int* in_sizes, int n_in,
                              void* d_out, int out_size, void* d_ws, size_t ws_size,
                              hipStream_t stream) {
    const float* x = (const float*)d_in[0];
    float* out = (float*)d_out;
    char* ws = (char*)d_ws;
    // workspace layout (~9.3 MB; all regions written before read each call):
    //   idx_buf:  16*50*1536 u8                      = 1,228,800 B @ 0
    //   ampu_buf: 16*30*1536 u32                     = 2,949,120 B @ 1,228,800
    //   Xp:       16 chunks * 16*768 complex double  = 3,145,728 B @ 4,177,920
    //   Xf:       16*768 complex double              =   196,608 B @ 7,323,648
    //   Sums:     800*31*18 u32                      = 1,785,600 B @ 7,520,256
    unsigned char* idx_buf = (unsigned char*)ws;
    unsigned int* ampu_buf = (unsigned int*)(ws + 1228800);
    double* Xp = (double*)(ws + 4177920);
    double* Xf = (double*)(ws + 7323648);
    unsigned int* Sums = (unsigned int*)(ws + 7520256);

    hipMemsetAsync(Sums, 0, (size_t)NBC * PHA_N * NROW * NBINS * 4, stream);
    dft_kernel<<<dim3(NBC, FMAX / 256, NCH), 256, 0, stream>>>(x, Xp);
    reduce_kernel<<<NBC * FMAX / 256, 256, 0, stream>>>(Xp, Xf);
    band_kernel<<<dim3(NBC, NBANDS, 2), 256, 0, stream>>>(Xf, idx_buf, ampu_buf);
    mi_part<<<dim3(NBC * PHA_N, QS), 256, 0, stream>>>(idx_buf, ampu_buf, Sums);
    mi_final<<<(NBC * PHA_N * AMP_N + 255) / 256, 256, 0, stream>>>(Sums, out);
}